// Round 11
// baseline (139.571 us; speedup 1.0000x reference)
//
#include <hip/hip_runtime.h>
#include <hip/hip_bf16.h>

typedef unsigned short u16;
typedef __attribute__((ext_vector_type(8))) unsigned short ushort8;
typedef __attribute__((ext_vector_type(8))) __bf16 bf16x8;
typedef __attribute__((ext_vector_type(4))) float f32x4;

// N=16, L=4096, IN_DIM=32, D=E=512
#define NB 16
#define SEQ 4096
#define DIM 512
#define INDIM 32
#define NTOK (NB * SEQ)    // 65536
#define WBM 128            // tokens per k_w tile
#define NTILE (NTOK / WBM) // 512 (32 per batch)

static __device__ __forceinline__ u16 f2bf(float f) {
    union { float f; unsigned u; } x; x.f = f;
    unsigned r = (x.u + 0x7FFFu + ((x.u >> 16) & 1u)) >> 16;
    return (u16)r;
}
static __device__ __forceinline__ float bf2f(u16 b) {
    union { unsigned u; float f; } x; x.u = ((unsigned)b) << 16;
    return x.f;
}

__device__ __forceinline__ float dot32(const float* __restrict__ w, const float* v) {
    const float4* a = (const float4*)w;
    float acc = 0.f;
    #pragma unroll
    for (int i = 0; i < 8; ++i) {
        float4 p = a[i];
        acc += p.x * v[4*i] + p.y * v[4*i+1] + p.z * v[4*i+2] + p.w * v[4*i+3];
    }
    return acc;
}

__device__ __forceinline__ float dot512(const float* __restrict__ w, const float* v) {
    const float4* a = (const float4*)w;
    float acc = 0.f;
    #pragma unroll 4
    for (int j = 0; j < 128; ++j) {
        float4 p = a[j];
        acc += p.x * v[4*j] + p.y * v[4*j+1] + p.z * v[4*j+2] + p.w * v[4*j+3];
    }
    return acc;
}

struct P {
    const float *x, *w_in, *b_in, *wq, *bq, *wk, *bk, *wv, *bv, *wo, *bo;
    const float *g1, *b1, *wff1, *bff1, *wff2, *bff2, *g2, *b2, *gf, *bfv, *wfc, *bfc;
    u16 *wk2b; float *bk2, *wv2, *wvb;
    float *bb, *wf1x, *wf1c, *wg1, *wb1;
    u16 *woT, *wff1g1T, *wff2T;
    float *q0, *xup, *zdp;
    int *cnt;
    float *out;
};

// ===================== k_p1: all input-only precomputes =====================
// grid 1744:
//   [0,512):    wk2b/bk2   (e = bid)
//   [512,1024): wv2/wvb    (e = bid-512)
//   [1024,1536): wf1x, wf1c, wg1, wb1, bb  (e = bid-1024)
//   [1536,1728): bf16 transposes MT[k][d]: m=0 wo, m=1 wff1*g1, m=2 wff2
//   [1728,1744): q0 per batch (direct from wq) + cnt[n]=0
__global__ __launch_bounds__(256) void k_p1(P p) {
    __shared__ float smem[64 * 65];   // 16.6 KiB, reused per segment
    int bid = blockIdx.x, tid = threadIdx.x;

    if (bid < 1024) {
        int mat = bid >> 9, e = bid & 511;   // 0=wk, 1=wv
        int kc = tid >> 5, j = tid & 31;
        const float* A = (mat == 0 ? p.wk : p.wv) + (long)e * DIM;
        float acc = 0.f, accb = 0.f;
        int d0 = kc * 64;
        #pragma unroll 8
        for (int i = 0; i < 64; ++i) {
            float a = A[d0 + i];
            acc  += a * p.w_in[(d0 + i) * INDIM + j];
            accb += a * p.b_in[d0 + i];
        }
        float* sA = smem;          // [8][32]
        float* sS = smem + 256;    // [8]
        sA[kc * 32 + j] = acc;
        if (j == 0) sS[kc] = accb;
        __syncthreads();
        if (tid < 32) {
            float s = 0.f;
            #pragma unroll
            for (int i = 0; i < 8; ++i) s += sA[i * 32 + tid];
            if (mat == 0) p.wk2b[e * INDIM + tid] = f2bf(s);
            else p.wv2[e * INDIM + tid] = s;
        } else if (tid == 32) {
            float s = 0.f;
            #pragma unroll
            for (int i = 0; i < 8; ++i) s += sS[i];
            if (mat == 0) p.bk2[e] = p.bk[e] + s;
            else p.wvb[e] = s + p.bv[e];
        }
    } else if (bid < 1536) {
        int e = bid - 1024;
        int kc = tid >> 5, j = tid & 31;
        const float* A = p.wff1 + (long)e * DIM;
        float accx = 0.f, accc = 0.f, accg = 0.f, accb1 = 0.f;
        int d0 = kc * 64;
        #pragma unroll 4
        for (int i = 0; i < 64; ++i) {
            int d = d0 + i;
            float a = A[d], g = p.g1[d], ag = a * g;
            accx  += ag * p.w_in[d * INDIM + j];
            accc  += ag * (p.b_in[d] + p.bo[d]);
            accg  += ag;
            accb1 += a * p.b1[d];
        }
        float* sA = smem;
        float* s0 = smem + 256;
        float* s1p = smem + 264;
        float* s2 = smem + 272;
        sA[kc * 32 + j] = accx;
        if (j == 0) { s0[kc] = accc; s1p[kc] = accg; s2[kc] = accb1; }
        __syncthreads();
        if (tid < 32) {
            float s = 0.f;
            #pragma unroll
            for (int i = 0; i < 8; ++i) s += sA[i * 32 + tid];
            p.wf1x[e * INDIM + tid] = s;
        } else if (tid == 32) {
            float s = 0.f;
            #pragma unroll
            for (int i = 0; i < 8; ++i) s += s0[i];
            p.wf1c[e] = s;
        } else if (tid == 33) {
            float s = 0.f;
            #pragma unroll
            for (int i = 0; i < 8; ++i) s += s1p[i];
            p.wg1[e] = s;
        } else if (tid == 34) {
            float s = 0.f;
            #pragma unroll
            for (int i = 0; i < 8; ++i) s += s2[i];
            p.wb1[e] = s;
        } else if (tid == 35) {
            p.bb[e] = p.b_in[e] + p.bo[e];
        }
    } else if (bid < 1728) {
        // transpose+cvt: MT[k][d] = bf16(M[d][k] * (m==1 ? g1[k] : 1)); 64x64 tiles
        int t = bid - 1536;            // 0..191
        int m = t >> 6;                // 0 wo, 1 wff1*g1, 2 wff2
        int tt = t & 63;
        int r = tt >> 3, c = tt & 7;   // d-tile, k-tile
        const float* M = (m == 0) ? p.wo : (m == 1 ? p.wff1 : p.wff2);
        u16* MT = (m == 0) ? p.woT : (m == 1 ? p.wff1g1T : p.wff2T);
        float* tile = smem;            // [64][65]
        int rr = tid >> 2, cc = (tid & 3) * 16;
        const float* src = M + (long)(r * 64 + rr) * DIM + c * 64 + cc;
        #pragma unroll
        for (int i = 0; i < 4; ++i) {
            float4 v = *(const float4*)(src + i * 4);
            tile[rr * 65 + cc + i * 4 + 0] = v.x;
            tile[rr * 65 + cc + i * 4 + 1] = v.y;
            tile[rr * 65 + cc + i * 4 + 2] = v.z;
            tile[rr * 65 + cc + i * 4 + 3] = v.w;
        }
        __syncthreads();
        int orr = tid >> 2, occ = (tid & 3) * 16;   // k-local, d-chunk
        float gk = (m == 1) ? p.g1[c * 64 + orr] : 1.f;
        u16 ob[16];
        #pragma unroll
        for (int i = 0; i < 16; ++i) ob[i] = f2bf(tile[(occ + i) * 65 + orr] * gk);
        u16* dst = MT + (long)(c * 64 + orr) * DIM + r * 64 + occ;
        *(ushort8*)dst = *(ushort8*)ob;
        *(ushort8*)(dst + 8) = *(ushort8*)(ob + 8);
    } else {
        // q0[n] = elu(wq @ (w_in@x0 + b_in) + bq) + 1, direct from raw weights
        int n = bid - 1728;
        float* sx0 = smem;        // 32
        float* sh = smem + 32;    // 512
        if (tid < INDIM) sx0[tid] = p.x[(long)n * SEQ * INDIM + tid];
        __syncthreads();
        #pragma unroll
        for (int rep = 0; rep < 2; ++rep) {
            int d = tid + rep * 256;
            sh[d] = p.b_in[d] + dot32(p.w_in + (long)d * INDIM, sx0);
        }
        __syncthreads();
        #pragma unroll
        for (int rep = 0; rep < 2; ++rep) {
            int e = tid + rep * 256;
            float a = p.bq[e] + dot512(p.wq + (long)e * DIM, sh);
            p.q0[n * DIM + e] = (a > 0.f) ? (a + 1.f) : __expf(a);
        }
        if (tid == 0) p.cnt[n] = 0;
    }
}

// ---------------- finalize helpers (256-thread) ----------------
__device__ __forceinline__ void reduce2_256(float a, float b, int tid, float* l16,
                                            float& oa, float& ob) {
    #pragma unroll
    for (int off = 1; off < 64; off <<= 1) {
        a += __shfl_xor(a, off, 64);
        b += __shfl_xor(b, off, 64);
    }
    int w = tid >> 6;
    if ((tid & 63) == 0) { l16[w] = a; l16[4 + w] = b; }
    __syncthreads();
    oa = l16[0] + l16[1] + l16[2] + l16[3];
    ob = l16[4] + l16[5] + l16[6] + l16[7];
    __syncthreads();
}

// coalesced GEMV: out_d = sum_k MT[k][d]*vec[k]; 4-way k-split over 4 waves.
__device__ __forceinline__ void gemv256(const u16* __restrict__ MT,
                                        const float* __restrict__ vec,
                                        float* __restrict__ spart,
                                        int tid, float& o0, float& o1) {
    int kc = tid >> 6, dg = tid & 63;
    float ps[8] = {};
    const u16* base = MT + (long)(kc * 128) * DIM + dg * 8;
    #pragma unroll 8
    for (int k8 = 0; k8 < 128; ++k8) {
        ushort8 w8 = *(const ushort8*)(base + (long)k8 * DIM);
        float fk = vec[kc * 128 + k8];
        #pragma unroll
        for (int j = 0; j < 8; ++j) ps[j] += bf2f(w8[j]) * fk;
    }
    #pragma unroll
    for (int j = 0; j < 8; ++j) spart[kc * DIM + dg * 8 + j] = ps[j];
    __syncthreads();
    float a0 = 0.f, a1 = 0.f;
    #pragma unroll
    for (int i = 0; i < 4; ++i) {
        a0 += spart[i * DIM + tid];
        a1 += spart[i * DIM + tid + 256];
    }
    o0 = a0; o1 = a1;
}

__device__ void phaseE256(const P& p, int n, int tid, char* smem) {
    float* sx0 = (float*)smem;          // 32
    float* sxu = sx0 + 32;              // 32
    float* sv  = sxu + 32;              // 512
    float* sf  = sv + 512;              // 512
    float* spart = sf + 512;            // 2048
    float* l16 = spart + 2048;          // 8
    float* szd = l16 + 8;               // 1  (~12.5 KiB total)
    if (tid < INDIM) {
        float a = 0.f;
        #pragma unroll 8
        for (int slot = 0; slot < 32; ++slot)
            a += p.xup[(n * 32 + slot) * INDIM + tid];
        sxu[tid] = a;
        sx0[tid] = p.x[(long)n * SEQ * INDIM + tid];
    } else if (tid == 32) {
        float z = 0.f;
        #pragma unroll 8
        for (int slot = 0; slot < 32; ++slot) z += p.zdp[n * 32 + slot];
        szd[0] = z;
    }
    __syncthreads();
    float zd = szd[0];
    float Z = 1.f / (zd + 1e-6f);
    float zz = zd * Z;
    int d0 = tid, d1 = tid + 256;

    // v = Z*(wv2@xu) + zz*wvb
    sv[d0] = Z * dot32(p.wv2 + (long)d0 * INDIM, sxu) + zz * p.wvb[d0];
    sv[d1] = Z * dot32(p.wv2 + (long)d1 * INDIM, sxu) + zz * p.wvb[d1];
    __syncthreads();

    // o = wo @ v
    float o0, o1;
    gemv256(p.woT, sv, spart, tid, o0, o1);

    // r = bb + w_in@x0 + o ; LN1
    float rd0 = p.bb[d0] + dot32(p.w_in + (long)d0 * INDIM, sx0) + o0;
    float rd1 = p.bb[d1] + dot32(p.w_in + (long)d1 * INDIM, sx0) + o1;
    sv[d0] = o0;   // GEMV-B input; fenced by reduce2's syncs
    sv[d1] = o1;
    float sum, sumsq;
    reduce2_256(rd0 + rd1, rd0 * rd0 + rd1 * rd1, tid, l16, sum, sumsq);
    float mu1 = sum * (1.f / DIM);
    float s1 = rsqrtf(sumsq * (1.f / DIM) - mu1 * mu1 + 1e-5f);
    float r1_0 = (rd0 - mu1) * s1 * p.g1[d0] + p.b1[d0];
    float r1_1 = (rd1 - mu1) * s1 * p.g1[d1] + p.b1[d1];

    // G = wf1x@x0 + (wff1*g1)@o + wf1c ; f = relu(fpre)
    float W0, W1;
    gemv256(p.wff1g1T, sv, spart, tid, W0, W1);
    float G0 = dot32(p.wf1x + (long)d0 * INDIM, sx0) + W0 + p.wf1c[d0];
    float G1 = dot32(p.wf1x + (long)d1 * INDIM, sx0) + W1 + p.wf1c[d1];
    float fp0 = s1 * (G0 - mu1 * p.wg1[d0]) + p.wb1[d0] + p.bff1[d0];
    float fp1 = s1 * (G1 - mu1 * p.wg1[d1]) + p.wb1[d1] + p.bff1[d1];
    __syncthreads();            // fence spart reads before GEMV-C writes
    sf[d0] = fmaxf(fp0, 0.f);
    sf[d1] = fmaxf(fp1, 0.f);
    __syncthreads();

    // y = r1 + wff2@f + bff2
    float ya0, ya1;
    gemv256(p.wff2T, sf, spart, tid, ya0, ya1);
    float y0 = r1_0 + p.bff2[d0] + ya0;
    float y1 = r1_1 + p.bff2[d1] + ya1;

    reduce2_256(y0 + y1, y0 * y0 + y1 * y1, tid, l16, sum, sumsq);
    float mu2 = sum * (1.f / DIM);
    float inv2 = rsqrtf(sumsq * (1.f / DIM) - mu2 * mu2 + 1e-5f);
    float h2_0 = (y0 - mu2) * inv2 * p.g2[d0] + p.b2[d0];
    float h2_1 = (y1 - mu2) * inv2 * p.g2[d1] + p.b2[d1];

    reduce2_256(h2_0 + h2_1, h2_0 * h2_0 + h2_1 * h2_1, tid, l16, sum, sumsq);
    float mu3 = sum * (1.f / DIM);
    float inv3 = rsqrtf(sumsq * (1.f / DIM) - mu3 * mu3 + 1e-5f);
    float h3_0 = (h2_0 - mu3) * inv3 * p.gf[d0] + p.bfv[d0];
    float h3_1 = (h2_1 - mu3) * inv3 * p.gf[d1] + p.bfv[d1];

    float pr = p.wfc[d0] * h3_0 + p.wfc[d1] * h3_1;
    float dummy;
    reduce2_256(pr, 0.f, tid, l16, sum, dummy);
    if (tid == 0) p.out[n] = sum + p.bfc[0];
}

// ===================== k_wE: 512 token tiles + fused per-batch finalize =====================
__global__ __launch_bounds__(256) void k_wE(P p) {
    __shared__ __align__(16) char smem[45056];
    __shared__ int sTicket;
    int tid = threadIdx.x;
    int tt = blockIdx.x;
    int lane = tid & 63, wid = tid >> 6;
    long tbase = (long)tt * WBM;
    int batch = (int)(tbase >> 12);

    u16* sB = (u16*)smem;                 // DIM*40 u16 = 40960 B
    float* sw = (float*)(smem + 40960);   // 512 B
    float* sxu8 = (float*)(smem + 41472); // 1024 B
    float* szz = (float*)(smem + 42496);  // 32 B

    // stage wk2b -> LDS (padded stride 40)
    #pragma unroll
    for (int pp = 0; pp < 8; ++pp) {
        int f = (pp * 256 + tid) * 8;
        int row = f >> 5, colc = f & 31;
        ushort8 v = *(const ushort8*)(p.wk2b + f);
        *(ushort8*)(sB + row * 40 + colc) = v;
    }

    int col = lane & 15;
    int koff = (lane >> 4) * 8;
    // A fragments direct from global x
    bf16x8 fa[2];
    #pragma unroll
    for (int mi = 0; mi < 2; ++mi) {
        const float* xr = p.x + (tbase + wid * 32 + mi * 16 + col) * INDIM + koff;
        float4 a0 = *(const float4*)(xr);
        float4 a1 = *(const float4*)(xr + 4);
        u16 tmp[8] = { f2bf(a0.x), f2bf(a0.y), f2bf(a0.z), f2bf(a0.w),
                       f2bf(a1.x), f2bf(a1.y), f2bf(a1.z), f2bf(a1.w) };
        fa[mi] = *(bf16x8*)tmp;
    }
    // q0/bk2 per-lane vectors from global (L2-resident)
    float q0v[32], bkv[32];
    #pragma unroll
    for (int ni = 0; ni < 32; ++ni) {
        q0v[ni] = p.q0[batch * DIM + ni * 16 + col];
        bkv[ni] = p.bk2[ni * 16 + col];
    }
    __syncthreads();   // sB ready

    f32x4 zero = {0.f, 0.f, 0.f, 0.f};
    float wpart[2][4] = {};
    #pragma unroll
    for (int nc = 0; nc < 4; ++nc) {
        bf16x8 fb[8];
        #pragma unroll
        for (int nj = 0; nj < 8; ++nj) {
            int row = (nc * 8 + nj) * 16 + col;
            fb[nj] = *(const bf16x8*)(sB + row * 40 + koff);
        }
        #pragma unroll
        for (int mi = 0; mi < 2; ++mi) {
            #pragma unroll
            for (int nj = 0; nj < 8; ++nj) {
                f32x4 acc = __builtin_amdgcn_mfma_f32_16x16x32_bf16(fa[mi], fb[nj], zero, 0, 0, 0);
                int ni = nc * 8 + nj;
                #pragma unroll
                for (int r = 0; r < 4; ++r) {
                    float v = acc[r] + bkv[ni];
                    v = (v > 0.f) ? (v + 1.f) : __expf(v);
                    wpart[mi][r] += v * q0v[ni];
                }
            }
        }
    }
    #pragma unroll
    for (int mi = 0; mi < 2; ++mi) {
        #pragma unroll
        for (int r = 0; r < 4; ++r) {
            float s = wpart[mi][r];
            s += __shfl_xor(s, 1, 64); s += __shfl_xor(s, 2, 64);
            s += __shfl_xor(s, 4, 64); s += __shfl_xor(s, 8, 64);
            if (col == 0) sw[wid * 32 + mi * 16 + (lane >> 4) * 4 + r] = s;
        }
    }
    __syncthreads();
    {
        int j = tid & 31, g = tid >> 5;
        float a = 0.f, z = 0.f;
        for (int tl = g; tl < WBM; tl += 8) {
            float wv_ = sw[tl];
            a += wv_ * p.x[(tbase + tl) * INDIM + j];
            if (j == 0) z += wv_;
        }
        sxu8[g * 32 + j] = a;
        if (j == 0) szz[g] = z;
    }
    __syncthreads();
    if (tid < 32) {
        float a = 0.f;
        #pragma unroll
        for (int g = 0; g < 8; ++g) a += sxu8[g * 32 + tid];
        p.xup[tt * INDIM + tid] = a;
    } else if (tid == 32) {
        float z = 0.f;
        #pragma unroll
        for (int g = 0; g < 8; ++g) z += szz[g];
        p.zdp[tt] = z;
    }

    // -------- per-batch completion ticket; last tile runs the finalize --------
    __threadfence();                 // release: xup/zdp visible device-wide
    __syncthreads();
    if (tid == 0) sTicket = atomicAdd(&p.cnt[batch], 1);
    __syncthreads();
    if (sTicket == 31) {
        __threadfence();             // acquire: see all 32 tiles' xup/zdp
        phaseE256(p, batch, tid, smem);
    }
}

extern "C" void kernel_launch(void* const* d_in, const int* in_sizes, int n_in,
                              void* d_out, int out_size, void* d_ws, size_t ws_size,
                              hipStream_t stream) {
    char* ws = (char*)d_ws;
    P p;
    p.x    = (const float*)d_in[0];
    p.w_in = (const float*)d_in[1];
    p.b_in = (const float*)d_in[2];
    p.wq   = (const float*)d_in[3];
    p.bq   = (const float*)d_in[4];
    p.wk   = (const float*)d_in[5];
    p.bk   = (const float*)d_in[6];
    p.wv   = (const float*)d_in[7];
    p.bv   = (const float*)d_in[8];
    p.wo   = (const float*)d_in[9];
    p.bo   = (const float*)d_in[10];
    p.g1   = (const float*)d_in[11];
    p.b1   = (const float*)d_in[12];
    p.wff1 = (const float*)d_in[13];
    p.bff1 = (const float*)d_in[14];
    p.wff2 = (const float*)d_in[15];
    p.bff2 = (const float*)d_in[16];
    p.g2   = (const float*)d_in[17];
    p.b2   = (const float*)d_in[18];
    p.gf   = (const float*)d_in[19];
    p.bfv  = (const float*)d_in[20];
    p.wfc  = (const float*)d_in[21];
    p.bfc  = (const float*)d_in[22];

    p.wk2b    = (u16*)  (ws + 0);          // 32 KiB
    p.bk2     = (float*)(ws + 32768);      // 2 KiB
    p.wv2     = (float*)(ws + 34816);      // 64 KiB
    p.wvb     = (float*)(ws + 100352);     // 2 KiB
    p.bb      = (float*)(ws + 102400);     // 2 KiB
    p.wf1x    = (float*)(ws + 104448);     // 64 KiB
    p.wf1c    = (float*)(ws + 169984);     // 2 KiB
    p.wg1     = (float*)(ws + 172032);     // 2 KiB
    p.wb1     = (float*)(ws + 174080);     // 2 KiB
    p.woT     = (u16*)  (ws + 176128);     // 512 KiB
    p.wff1g1T = (u16*)  (ws + 700416);     // 512 KiB
    p.wff2T   = (u16*)  (ws + 1224704);    // 512 KiB
    p.q0      = (float*)(ws + 1748992);    // 32 KiB
    p.xup     = (float*)(ws + 1781760);    // 64 KiB  [512][32]
    p.zdp     = (float*)(ws + 1847296);    // 2 KiB   [512]
    p.cnt     = (int*)  (ws + 1849344);    // 64 B    [16]
    p.out     = (float*)d_out;

    k_p1<<<1744, 256, 0, stream>>>(p);
    k_wE<<<NTILE, 256, 0, stream>>>(p);
}

// Round 12
// 98.132 us; speedup vs baseline: 1.4223x; 1.4223x over previous
//
#include <hip/hip_runtime.h>
#include <hip/hip_bf16.h>

typedef unsigned short u16;
typedef __attribute__((ext_vector_type(8))) unsigned short ushort8;
typedef __attribute__((ext_vector_type(8))) __bf16 bf16x8;
typedef __attribute__((ext_vector_type(4))) float f32x4;

// N=16, L=4096, IN_DIM=32, D=E=512
#define NB 16
#define SEQ 4096
#define DIM 512
#define INDIM 32
#define NTOK (NB * SEQ)    // 65536
#define WBM 128            // tokens per k_w tile
#define NTILE (NTOK / WBM) // 512

static __device__ __forceinline__ u16 f2bf(float f) {
    union { float f; unsigned u; } x; x.f = f;
    unsigned r = (x.u + 0x7FFFu + ((x.u >> 16) & 1u)) >> 16;
    return (u16)r;
}
static __device__ __forceinline__ float bf2f(u16 b) {
    union { unsigned u; float f; } x; x.u = ((unsigned)b) << 16;
    return x.f;
}

__device__ __forceinline__ float dot32(const float* __restrict__ w, const float* v) {
    const float4* a = (const float4*)w;
    float acc = 0.f;
    #pragma unroll
    for (int i = 0; i < 8; ++i) {
        float4 p = a[i];
        acc += p.x * v[4*i] + p.y * v[4*i+1] + p.z * v[4*i+2] + p.w * v[4*i+3];
    }
    return acc;
}

__device__ __forceinline__ float dot512(const float* __restrict__ w, const float* v) {
    const float4* a = (const float4*)w;
    float acc = 0.f;
    #pragma unroll 4
    for (int j = 0; j < 128; ++j) {
        float4 p = a[j];
        acc += p.x * v[4*j] + p.y * v[4*j+1] + p.z * v[4*j+2] + p.w * v[4*j+3];
    }
    return acc;
}

// ===================== k_p1: input-only precomputes =====================
// grid 1872:
//   [0,1024):    wk rows -> wk2b/bk2 (mat0) ; wv rows -> wv2/wvb (mat1)
//   [1024,1536): wff1 rows -> wf1x, wf1c, wg1, wb1, bb
//   [1536,1792): wfop K-split GEMM: (wff1*g1)@wo partials [4][512][512]
//   [1792,1856): wff2 -> bf16 transpose wff2T[k][d]
//   [1856,1872): q0 per batch (direct from raw wq)
__global__ __launch_bounds__(256) void k_p1(
    const float* __restrict__ x,
    const float* __restrict__ w_in, const float* __restrict__ b_in,
    const float* __restrict__ wq, const float* __restrict__ bq,
    const float* __restrict__ wk, const float* __restrict__ bk,
    const float* __restrict__ wv, const float* __restrict__ bv,
    const float* __restrict__ wo, const float* __restrict__ bo,
    const float* __restrict__ g1, const float* __restrict__ b1,
    const float* __restrict__ wff1, const float* __restrict__ wff2,
    u16* __restrict__ wk2b, float* __restrict__ bk2,
    float* __restrict__ wv2, float* __restrict__ wvb,
    float* __restrict__ wf1x, float* __restrict__ wf1c,
    float* __restrict__ wg1, float* __restrict__ wb1, float* __restrict__ bb,
    float* __restrict__ wfop, u16* __restrict__ wff2T,
    float* __restrict__ q0) {
    __shared__ float smem[64 * 65];   // 16.6 KiB, reused per segment
    int bid = blockIdx.x, tid = threadIdx.x;

    if (bid < 1024) {
        int mat = bid >> 9, e = bid & 511;   // 0=wk, 1=wv
        int kc = tid >> 5, j = tid & 31;
        const float* A = (mat == 0 ? wk : wv) + (long)e * DIM;
        float acc = 0.f, accb = 0.f;
        int d0 = kc * 64;
        #pragma unroll 8
        for (int i = 0; i < 64; ++i) {
            float a = A[d0 + i];
            acc  += a * w_in[(d0 + i) * INDIM + j];
            accb += a * b_in[d0 + i];
        }
        float* sA = smem;          // [8][32]
        float* sS = smem + 256;    // [8]
        sA[kc * 32 + j] = acc;
        if (j == 0) sS[kc] = accb;
        __syncthreads();
        if (tid < 32) {
            float s = 0.f;
            #pragma unroll
            for (int i = 0; i < 8; ++i) s += sA[i * 32 + tid];
            if (mat == 0) wk2b[e * INDIM + tid] = f2bf(s);
            else wv2[e * INDIM + tid] = s;
        } else if (tid == 32) {
            float s = 0.f;
            #pragma unroll
            for (int i = 0; i < 8; ++i) s += sS[i];
            if (mat == 0) bk2[e] = bk[e] + s;
            else wvb[e] = s + bv[e];
        }
    } else if (bid < 1536) {
        int e = bid - 1024;
        int kc = tid >> 5, j = tid & 31;
        const float* A = wff1 + (long)e * DIM;
        float accx = 0.f, accc = 0.f, accg = 0.f, accb1 = 0.f;
        int d0 = kc * 64;
        #pragma unroll 4
        for (int i = 0; i < 64; ++i) {
            int d = d0 + i;
            float a = A[d], g = g1[d], ag = a * g;
            accx  += ag * w_in[d * INDIM + j];
            accc  += ag * (b_in[d] + bo[d]);
            accg  += ag;
            accb1 += a * b1[d];
        }
        float* sA = smem;
        float* s0 = smem + 256;
        float* s1p = smem + 264;
        float* s2 = smem + 272;
        sA[kc * 32 + j] = accx;
        if (j == 0) { s0[kc] = accc; s1p[kc] = accg; s2[kc] = accb1; }
        __syncthreads();
        if (tid < 32) {
            float s = 0.f;
            #pragma unroll
            for (int i = 0; i < 8; ++i) s += sA[i * 32 + tid];
            wf1x[e * INDIM + tid] = s;
        } else if (tid == 32) {
            float s = 0.f;
            #pragma unroll
            for (int i = 0; i < 8; ++i) s += s0[i];
            wf1c[e] = s;
        } else if (tid == 33) {
            float s = 0.f;
            #pragma unroll
            for (int i = 0; i < 8; ++i) s += s1p[i];
            wg1[e] = s;
        } else if (tid == 34) {
            float s = 0.f;
            #pragma unroll
            for (int i = 0; i < 8; ++i) s += s2[i];
            wb1[e] = s;
        } else if (tid == 35) {
            bb[e] = b_in[e] + bo[e];
        }
    } else if (bid < 1792) {
        // wfop partial: C[e0..+64][d0..+64] = sum_k (wff1*g1)[e][k]*wo[k][d], k in kp*128..+128
        int t = bid - 1536;
        int kp = t >> 6, et = (t >> 3) & 7, dt = t & 7;
        float* sA = smem;              // [32][65]
        float* sB = smem + 32 * 65;    // [32][64]
        int e0 = et * 64, d0 = dt * 64;
        float c[4][4] = {};
        for (int kc2 = 0; kc2 < 4; ++kc2) {
            int k0 = kp * 128 + kc2 * 32;
            {
                int e = tid >> 2, kg = (tid & 3) * 8;
                const float* src = wff1 + (long)(e0 + e) * DIM + k0 + kg;
                const float* gp = g1 + k0 + kg;
                #pragma unroll
                for (int q = 0; q < 8; ++q)
                    sA[(kg + q) * 65 + e] = src[q] * gp[q];
            }
            {
                int k = tid >> 3, dg = (tid & 7) * 8;
                const float* src = wo + (long)(k0 + k) * DIM + d0 + dg;
                float4 v0 = *(const float4*)src;
                float4 v1 = *(const float4*)(src + 4);
                float* dst = sB + k * 64 + dg;
                *(float4*)dst = v0;
                *(float4*)(dst + 4) = v1;
            }
            __syncthreads();
            int ty4 = (tid >> 4) * 4, tx4 = (tid & 15) * 4;
            #pragma unroll 8
            for (int k = 0; k < 32; ++k) {
                float a[4], b[4];
                #pragma unroll
                for (int i = 0; i < 4; ++i) a[i] = sA[k * 65 + ty4 + i];
                #pragma unroll
                for (int jv = 0; jv < 4; ++jv) b[jv] = sB[k * 64 + tx4 + jv];
                #pragma unroll
                for (int i = 0; i < 4; ++i)
                    #pragma unroll
                    for (int jv = 0; jv < 4; ++jv) c[i][jv] += a[i] * b[jv];
            }
            __syncthreads();
        }
        int ty4 = (tid >> 4) * 4, tx4 = (tid & 15) * 4;
        float* base = wfop + (long)kp * DIM * DIM + (long)(e0 + ty4) * DIM + d0 + tx4;
        #pragma unroll
        for (int i = 0; i < 4; ++i) {
            float4 v = { c[i][0], c[i][1], c[i][2], c[i][3] };
            *(float4*)(base + (long)i * DIM) = v;
        }
    } else if (bid < 1856) {
        // transpose+cvt: wff2T[k][d] = bf16(wff2[d][k]); 64x64 tiles
        int t = bid - 1792;            // 0..63
        int r = t >> 3, c = t & 7;     // d-tile, k-tile
        float* tile = smem;            // [64][65]
        int rr = tid >> 2, cc = (tid & 3) * 16;
        const float* src = wff2 + (long)(r * 64 + rr) * DIM + c * 64 + cc;
        #pragma unroll
        for (int i = 0; i < 4; ++i) {
            float4 v = *(const float4*)(src + i * 4);
            tile[rr * 65 + cc + i * 4 + 0] = v.x;
            tile[rr * 65 + cc + i * 4 + 1] = v.y;
            tile[rr * 65 + cc + i * 4 + 2] = v.z;
            tile[rr * 65 + cc + i * 4 + 3] = v.w;
        }
        __syncthreads();
        int orr = tid >> 2, occ = (tid & 3) * 16;   // k-local, d-chunk
        u16 ob[16];
        #pragma unroll
        for (int i = 0; i < 16; ++i) ob[i] = f2bf(tile[(occ + i) * 65 + orr]);
        u16* dst = wff2T + (long)(c * 64 + orr) * DIM + r * 64 + occ;
        *(ushort8*)dst = *(ushort8*)ob;
        *(ushort8*)(dst + 8) = *(ushort8*)(ob + 8);
    } else {
        // q0[n] = elu(wq @ (w_in@x0 + b_in) + bq) + 1, direct from raw weights
        int n = bid - 1856;
        float* sx0 = smem;        // 32
        float* sh = smem + 32;    // 512
        if (tid < INDIM) sx0[tid] = x[(long)n * SEQ * INDIM + tid];
        __syncthreads();
        #pragma unroll
        for (int rep = 0; rep < 2; ++rep) {
            int d = tid + rep * 256;
            sh[d] = b_in[d] + dot32(w_in + (long)d * INDIM, sx0);
        }
        __syncthreads();
        #pragma unroll
        for (int rep = 0; rep < 2; ++rep) {
            int e = tid + rep * 256;
            float a = bq[e] + dot512(wq + (long)e * DIM, sh);
            q0[n * DIM + e] = (a > 0.f) ? (a + 1.f) : __expf(a);
        }
    }
}

// ===================== k_wp2: [0,512)=p2 rows ; [512,1024)=k_w tiles =====================
__global__ __launch_bounds__(256) void k_wp2(
    const float* __restrict__ x,
    const float* __restrict__ wo, const float* __restrict__ wfop,
    const float* __restrict__ wv2, const float* __restrict__ wvb,
    const float* __restrict__ q0,
    const u16* __restrict__ wk2b, const float* __restrict__ bk2,
    float* __restrict__ wo2, float* __restrict__ wob,
    float* __restrict__ wf1u, float* __restrict__ wf1w,
    float* __restrict__ xup, float* __restrict__ zdp) {
    __shared__ __align__(16) char smem[43584];
    int bid = blockIdx.x, tid = threadIdx.x;

    if (bid < 512) {
        // p2 row: wo2/wob, wf1u/wf1w for e=bid
        int e = bid;
        int kc = tid >> 5, j = tid & 31;
        const float* wor = wo + (long)e * DIM;
        const float* f0 = wfop + (long)e * DIM;
        float acco = 0.f, accu = 0.f, ao_b = 0.f, au_b = 0.f;
        int d0 = kc * 64;
        #pragma unroll 4
        for (int i = 0; i < 64; ++i) {
            int d = d0 + i;
            float a_o = wor[d];
            float a_f = f0[d] + f0[d + DIM * DIM] + f0[d + 2 * DIM * DIM] + f0[d + 3 * DIM * DIM];
            float wvj = wv2[d * INDIM + j];
            acco += a_o * wvj;
            accu += a_f * wvj;
            float wb = wvb[d];
            ao_b += a_o * wb;
            au_b += a_f * wb;
        }
        float* sO = (float*)smem;        // [8][32]
        float* sU = sO + 256;            // [8][32]
        float* sSb = sO + 512;           // [8][2]
        sO[kc * 32 + j] = acco;
        sU[kc * 32 + j] = accu;
        if (j == 0) { sSb[kc * 2] = ao_b; sSb[kc * 2 + 1] = au_b; }
        __syncthreads();
        if (tid < 32) {
            float s = 0.f;
            #pragma unroll
            for (int i = 0; i < 8; ++i) s += sO[i * 32 + tid];
            wo2[e * INDIM + tid] = s;
        } else if (tid < 64) {
            float s = 0.f;
            #pragma unroll
            for (int i = 0; i < 8; ++i) s += sU[i * 32 + (tid - 32)];
            wf1u[e * INDIM + (tid - 32)] = s;
        } else if (tid == 64) {
            float s = 0.f;
            #pragma unroll
            for (int i = 0; i < 8; ++i) s += sSb[i * 2];
            wob[e] = s;
        } else if (tid == 65) {
            float s = 0.f;
            #pragma unroll
            for (int i = 0; i < 8; ++i) s += sSb[i * 2 + 1];
            wf1w[e] = s;
        }
        return;
    }

    // ---- k_w tile (q0 from global; r11-verified math) ----
    int tt = bid - 512;
    int lane = tid & 63, wid = tid >> 6;
    long tbase = (long)tt * WBM;
    int batch = (int)(tbase >> 12);
    u16* sB = (u16*)smem;                 // 40960 B
    float* sw = (float*)(smem + 40960);   // 512 B
    float* sxu8 = (float*)(smem + 41472); // 1024 B
    float* szz = (float*)(smem + 42496);  // 32 B

    #pragma unroll
    for (int pp = 0; pp < 8; ++pp) {
        int f = (pp * 256 + tid) * 8;
        int row = f >> 5, colc = f & 31;
        ushort8 v = *(const ushort8*)(wk2b + f);
        *(ushort8*)(sB + row * 40 + colc) = v;
    }

    int col = lane & 15;
    int koff = (lane >> 4) * 8;
    bf16x8 fa[2];
    #pragma unroll
    for (int mi = 0; mi < 2; ++mi) {
        const float* xr = x + (tbase + wid * 32 + mi * 16 + col) * INDIM + koff;
        float4 a0 = *(const float4*)(xr);
        float4 a1 = *(const float4*)(xr + 4);
        u16 tmp[8] = { f2bf(a0.x), f2bf(a0.y), f2bf(a0.z), f2bf(a0.w),
                       f2bf(a1.x), f2bf(a1.y), f2bf(a1.z), f2bf(a1.w) };
        fa[mi] = *(bf16x8*)tmp;
    }
    float q0v[32], bkv[32];
    #pragma unroll
    for (int ni = 0; ni < 32; ++ni) {
        q0v[ni] = q0[batch * DIM + ni * 16 + col];
        bkv[ni] = bk2[ni * 16 + col];
    }
    __syncthreads();   // sB ready

    f32x4 zero = {0.f, 0.f, 0.f, 0.f};
    float wpart[2][4] = {};
    #pragma unroll
    for (int nc = 0; nc < 4; ++nc) {
        bf16x8 fb[8];
        #pragma unroll
        for (int nj = 0; nj < 8; ++nj) {
            int row = (nc * 8 + nj) * 16 + col;
            fb[nj] = *(const bf16x8*)(sB + row * 40 + koff);
        }
        #pragma unroll
        for (int mi = 0; mi < 2; ++mi) {
            #pragma unroll
            for (int nj = 0; nj < 8; ++nj) {
                f32x4 acc = __builtin_amdgcn_mfma_f32_16x16x32_bf16(fa[mi], fb[nj], zero, 0, 0, 0);
                int ni = nc * 8 + nj;
                #pragma unroll
                for (int r = 0; r < 4; ++r) {
                    float v = acc[r] + bkv[ni];
                    v = (v > 0.f) ? (v + 1.f) : __expf(v);
                    wpart[mi][r] += v * q0v[ni];
                }
            }
        }
    }
    #pragma unroll
    for (int mi = 0; mi < 2; ++mi) {
        #pragma unroll
        for (int r = 0; r < 4; ++r) {
            float s = wpart[mi][r];
            s += __shfl_xor(s, 1, 64); s += __shfl_xor(s, 2, 64);
            s += __shfl_xor(s, 4, 64); s += __shfl_xor(s, 8, 64);
            if (col == 0) sw[wid * 32 + mi * 16 + (lane >> 4) * 4 + r] = s;
        }
    }
    __syncthreads();
    {
        int j = tid & 31, g = tid >> 5;
        float a = 0.f, z = 0.f;
        for (int tl = g; tl < WBM; tl += 8) {
            float wv_ = sw[tl];
            a += wv_ * x[(tbase + tl) * INDIM + j];
            if (j == 0) z += wv_;
        }
        sxu8[g * 32 + j] = a;
        if (j == 0) szz[g] = z;
    }
    __syncthreads();
    if (tid < 32) {
        float a = 0.f;
        #pragma unroll
        for (int g = 0; g < 8; ++g) a += sxu8[g * 32 + tid];
        xup[tt * INDIM + tid] = a;
    } else if (tid == 32) {
        float z = 0.f;
        #pragma unroll
        for (int g = 0; g < 8; ++g) z += szz[g];
        zdp[tt] = z;
    }
}

// ===================== k_final: dot32s + one coalesced GEMV + LNs =====================
__device__ __forceinline__ void reduce2_512(float a, float b, int tid, float* l16,
                                            float& oa, float& ob) {
    #pragma unroll
    for (int off = 1; off < 64; off <<= 1) {
        a += __shfl_xor(a, off, 64);
        b += __shfl_xor(b, off, 64);
    }
    int w = tid >> 6;
    if ((tid & 63) == 0) { l16[w] = a; l16[8 + w] = b; }
    __syncthreads();
    float ra = 0.f, rb = 0.f;
    #pragma unroll
    for (int i = 0; i < 8; ++i) { ra += l16[i]; rb += l16[8 + i]; }
    oa = ra; ob = rb;
    __syncthreads();
}

__global__ __launch_bounds__(512) void k_final(
    const float* __restrict__ x, const float* __restrict__ w_in,
    const float* __restrict__ wo2, const float* __restrict__ wob,
    const float* __restrict__ bb,
    const float* __restrict__ wf1x, const float* __restrict__ wf1u,
    const float* __restrict__ wf1w, const float* __restrict__ wf1c,
    const float* __restrict__ wg1, const float* __restrict__ wb1,
    const float* __restrict__ g1, const float* __restrict__ b1,
    const float* __restrict__ bff1, const float* __restrict__ bff2,
    const u16* __restrict__ wff2T,
    const float* __restrict__ g2, const float* __restrict__ b2,
    const float* __restrict__ gf, const float* __restrict__ bfv,
    const float* __restrict__ wfc, const float* __restrict__ bfc,
    const float* __restrict__ xup, const float* __restrict__ zdp,
    float* __restrict__ out) {
    __shared__ float sx0[INDIM], sxu[INDIM];
    __shared__ float sf[DIM];
    __shared__ float spart[8][DIM];   // 16 KiB
    __shared__ float l16[16];
    __shared__ float szd;
    int n = blockIdx.x, tid = threadIdx.x, d = tid;
    if (tid < INDIM) {
        float a = 0.f;
        #pragma unroll 8
        for (int slot = 0; slot < 32; ++slot)
            a += xup[(n * 32 + slot) * INDIM + tid];
        sxu[tid] = a;
        sx0[tid] = x[(long)n * SEQ * INDIM + tid];
    } else if (tid == 32) {
        float z = 0.f;
        #pragma unroll 8
        for (int slot = 0; slot < 32; ++slot) z += zdp[n * 32 + slot];
        szd = z;
    }
    __syncthreads();
    float zd = szd;
    float Z = 1.f / (zd + 1e-6f);
    float zz = zd * Z;

    float rd = bb[d] + zz * wob[d] + dot32(w_in + d * INDIM, sx0)
             + Z * dot32(wo2 + d * INDIM, sxu);
    float sum, sumsq;
    reduce2_512(rd, rd * rd, tid, l16, sum, sumsq);
    float mu1 = sum * (1.f / DIM);
    float s1 = rsqrtf(sumsq * (1.f / DIM) - mu1 * mu1 + 1e-5f);
    float r1 = (rd - mu1) * s1 * g1[d] + b1[d];

    float G = dot32(wf1x + d * INDIM, sx0) + Z * dot32(wf1u + d * INDIM, sxu)
            + zz * wf1w[d] + wf1c[d];
    float fp = s1 * (G - mu1 * wg1[d]) + wb1[d] + bff1[d];
    sf[d] = fmaxf(fp, 0.f);
    __syncthreads();

    // y = r1 + wff2 @ f + bff2 — coalesced over wff2T[k][d], 8-way k-split
    {
        int kc = tid >> 6, dg = tid & 63;
        float ps[8] = {};
        const u16* base = wff2T + (long)(kc * 64) * DIM + dg * 8;
        #pragma unroll 8
        for (int k8 = 0; k8 < 64; ++k8) {
            ushort8 w8 = *(const ushort8*)(base + (long)k8 * DIM);
            float fk = sf[kc * 64 + k8];
            #pragma unroll
            for (int j = 0; j < 8; ++j) ps[j] += bf2f(w8[j]) * fk;
        }
        #pragma unroll
        for (int j = 0; j < 8; ++j) spart[kc][dg * 8 + j] = ps[j];
    }
    __syncthreads();
    float acc = 0.f;
    #pragma unroll
    for (int i = 0; i < 8; ++i) acc += spart[i][d];
    float y = r1 + bff2[d] + acc;

    reduce2_512(y, y * y, tid, l16, sum, sumsq);
    float mu2 = sum * (1.f / DIM);
    float inv2 = rsqrtf(sumsq * (1.f / DIM) - mu2 * mu2 + 1e-5f);
    float h2 = (y - mu2) * inv2 * g2[d] + b2[d];

    reduce2_512(h2, h2 * h2, tid, l16, sum, sumsq);
    float mu3 = sum * (1.f / DIM);
    float inv3 = rsqrtf(sumsq * (1.f / DIM) - mu3 * mu3 + 1e-5f);
    float h3 = (h2 - mu3) * inv3 * gf[d] + bfv[d];

    float pfc = wfc[d] * h3;
    float dummy;
    reduce2_512(pfc, 0.f, tid, l16, sum, dummy);
    if (tid == 0) out[n] = sum + bfc[0];
}

extern "C" void kernel_launch(void* const* d_in, const int* in_sizes, int n_in,
                              void* d_out, int out_size, void* d_ws, size_t ws_size,
                              hipStream_t stream) {
    const float* x    = (const float*)d_in[0];
    const float* w_in = (const float*)d_in[1];
    const float* b_in = (const float*)d_in[2];
    const float* wq   = (const float*)d_in[3];
    const float* bq   = (const float*)d_in[4];
    const float* wk   = (const float*)d_in[5];
    const float* bk   = (const float*)d_in[6];
    const float* wv   = (const float*)d_in[7];
    const float* bv   = (const float*)d_in[8];
    const float* wo   = (const float*)d_in[9];
    const float* bo   = (const float*)d_in[10];
    const float* g1   = (const float*)d_in[11];
    const float* b1   = (const float*)d_in[12];
    const float* wff1 = (const float*)d_in[13];
    const float* bff1 = (const float*)d_in[14];
    const float* wff2 = (const float*)d_in[15];
    const float* bff2 = (const float*)d_in[16];
    const float* g2   = (const float*)d_in[17];
    const float* b2   = (const float*)d_in[18];
    const float* gf   = (const float*)d_in[19];
    const float* bf   = (const float*)d_in[20];
    const float* wfc  = (const float*)d_in[21];
    const float* bfc  = (const float*)d_in[22];

    char* ws = (char*)d_ws;
    u16*   wk2b  = (u16*)  (ws + 0);          // 32 KiB
    float* bk2   = (float*)(ws + 32768);      // 2 KiB
    float* wv2   = (float*)(ws + 34816);      // 64 KiB
    float* wvb   = (float*)(ws + 100352);     // 2 KiB
    float* bb    = (float*)(ws + 102400);     // 2 KiB
    float* wf1x  = (float*)(ws + 104448);     // 64 KiB
    float* wf1c  = (float*)(ws + 169984);     // 2 KiB
    float* wg1   = (float*)(ws + 172032);     // 2 KiB
    float* wb1   = (float*)(ws + 174080);     // 2 KiB
    float* wo2   = (float*)(ws + 176128);     // 64 KiB
    float* wob   = (float*)(ws + 241664);     // 2 KiB
    float* wf1u  = (float*)(ws + 243712);     // 64 KiB
    float* wf1w  = (float*)(ws + 309248);     // 2 KiB
    u16*   wff2T = (u16*)  (ws + 311296);     // 512 KiB
    float* q0    = (float*)(ws + 835584);     // 32 KiB
    float* xup   = (float*)(ws + 868352);     // 64 KiB  [512][32]
    float* zdp   = (float*)(ws + 933888);     // 2 KiB   [512]
    float* wfop  = (float*)(ws + 935936);     // 4 MiB   [4][512][512]

    k_p1<<<1872, 256, 0, stream>>>(x, w_in, b_in, wq, bq, wk, bk, wv, bv, wo, bo,
                                   g1, b1, wff1, wff2,
                                   wk2b, bk2, wv2, wvb,
                                   wf1x, wf1c, wg1, wb1, bb,
                                   wfop, wff2T, q0);
    k_wp2<<<1024, 256, 0, stream>>>(x, wo, wfop, wv2, wvb, q0, wk2b, bk2,
                                    wo2, wob, wf1u, wf1w, xup, zdp);
    k_final<<<NB, 512, 0, stream>>>(x, w_in, wo2, wob, bb, wf1x, wf1u, wf1w, wf1c,
                                    wg1, wb1, g1, b1, bff1, bff2, wff2T,
                                    g2, b2, gf, bf, wfc, bfc, xup, zdp,
                                    (float*)d_out);
}

// Round 13
// 64.678 us; speedup vs baseline: 2.1579x; 1.5172x over previous
//
#include <hip/hip_runtime.h>
#include <hip/hip_bf16.h>

typedef unsigned short u16;
typedef __attribute__((ext_vector_type(8))) unsigned short ushort8;
typedef __attribute__((ext_vector_type(8))) __bf16 bf16x8;
typedef __attribute__((ext_vector_type(4))) float f32x4;

// N=16, L=4096, IN_DIM=32, D=E=512
#define NB 16
#define SEQ 4096
#define DIM 512
#define INDIM 32
#define NTOK (NB * SEQ)    // 65536
#define WBM 128            // tokens per k_w tile
#define NTILE (NTOK / WBM) // 512

static __device__ __forceinline__ u16 f2bf(float f) {
    union { float f; unsigned u; } x; x.f = f;
    unsigned r = (x.u + 0x7FFFu + ((x.u >> 16) & 1u)) >> 16;
    return (u16)r;
}
static __device__ __forceinline__ float bf2f(u16 b) {
    union { unsigned u; float f; } x; x.u = ((unsigned)b) << 16;
    return x.f;
}

__device__ __forceinline__ float dot32(const float* __restrict__ w, const float* v) {
    const float4* a = (const float4*)w;
    float acc = 0.f;
    #pragma unroll
    for (int i = 0; i < 8; ++i) {
        float4 p = a[i];
        acc += p.x * v[4*i] + p.y * v[4*i+1] + p.z * v[4*i+2] + p.w * v[4*i+3];
    }
    return acc;
}

// ===================== k_p1: input-only precomputes (throughput-tuned) =====================
// grid 704:
//   [0,384):   mats wq/wk/wv -> wq2/bq2, wk2b/bk2, wv2/wvb. 4 rows/block, float4 w_in loads.
//   [384,512): wff1 rows -> wf1x, wf1c, wg1, wb1, bb. 4 rows/block.
//   [512,704): bf16 transposes MT[k][d]: m=0 wo, m=1 wff1*g1, m=2 wff2 (64 tiles each)
__global__ __launch_bounds__(256) void k_p1(
    const float* __restrict__ x,
    const float* __restrict__ w_in, const float* __restrict__ b_in,
    const float* __restrict__ wq, const float* __restrict__ bq,
    const float* __restrict__ wk, const float* __restrict__ bk,
    const float* __restrict__ wv, const float* __restrict__ bv,
    const float* __restrict__ wo, const float* __restrict__ bo,
    const float* __restrict__ g1, const float* __restrict__ b1,
    const float* __restrict__ wff1, const float* __restrict__ wff2,
    float* __restrict__ wq2, float* __restrict__ bq2,
    u16* __restrict__ wk2b, float* __restrict__ bk2,
    float* __restrict__ wv2, float* __restrict__ wvb,
    float* __restrict__ wf1x, float* __restrict__ wf1c,
    float* __restrict__ wg1, float* __restrict__ wb1, float* __restrict__ bb,
    u16* __restrict__ woT, u16* __restrict__ wff1g1T, u16* __restrict__ wff2T) {
    __shared__ float smem[64 * 65];   // 16.6 KiB, reused per segment
    int bid = blockIdx.x, tid = threadIdx.x;

    if (bid < 384) {
        // 4 rows/block: row=tid>>6, kc=(tid>>3)&7 (64-k chunk), j4=tid&7 (float4 col group)
        int mat = bid >> 7, e0 = (bid & 127) * 4;
        int row = tid >> 6, kc = (tid >> 3) & 7, j4 = tid & 7;
        const float* A = (mat == 0 ? wq : (mat == 1 ? wk : wv))
                       + (long)(e0 + row) * DIM + kc * 64;
        const float* wbase = w_in + (kc * 64) * INDIM + j4 * 4;
        const float* bbase = b_in + kc * 64;
        float a0 = 0.f, a1 = 0.f, a2 = 0.f, a3 = 0.f, accb = 0.f;
        #pragma unroll 8
        for (int i = 0; i < 64; ++i) {
            float a = A[i];
            float4 w4 = *(const float4*)(wbase + i * INDIM);
            a0 += a * w4.x; a1 += a * w4.y; a2 += a * w4.z; a3 += a * w4.w;
            accb += a * bbase[i];
        }
        float* red  = smem;              // [4][8][33]
        float* redb = smem + 4 * 8 * 33; // [4][8]
        int rb = (row * 8 + kc) * 33 + j4 * 4;
        red[rb + 0] = a0; red[rb + 1] = a1; red[rb + 2] = a2; red[rb + 3] = a3;
        if (j4 == 0) redb[row * 8 + kc] = accb;
        __syncthreads();
        if (tid < 128) {
            int r = tid >> 5, j = tid & 31;
            float s = 0.f;
            #pragma unroll
            for (int k2 = 0; k2 < 8; ++k2) s += red[(r * 8 + k2) * 33 + j];
            int e = e0 + r;
            if (mat == 0) wq2[e * INDIM + j] = s;
            else if (mat == 1) wk2b[e * INDIM + j] = f2bf(s);
            else wv2[e * INDIM + j] = s;
        } else if (tid < 132) {
            int r = tid - 128;
            float s = 0.f;
            #pragma unroll
            for (int k2 = 0; k2 < 8; ++k2) s += redb[r * 8 + k2];
            int e = e0 + r;
            if (mat == 0) bq2[e] = bq[e] + s;
            else if (mat == 1) bk2[e] = bk[e] + s;
            else wvb[e] = s + bv[e];
        }
    } else if (bid < 512) {
        int e0 = (bid - 384) * 4;
        int row = tid >> 6, kc = (tid >> 3) & 7, j4 = tid & 7;
        const float* A = wff1 + (long)(e0 + row) * DIM + kc * 64;
        const float* wbase = w_in + (kc * 64) * INDIM + j4 * 4;
        int dbase = kc * 64;
        float a0 = 0.f, a1 = 0.f, a2 = 0.f, a3 = 0.f;
        float accc = 0.f, accg = 0.f, accb1 = 0.f;
        #pragma unroll 4
        for (int i = 0; i < 64; ++i) {
            int d = dbase + i;
            float a = A[i], g = g1[d], ag = a * g;
            float4 w4 = *(const float4*)(wbase + i * INDIM);
            a0 += ag * w4.x; a1 += ag * w4.y; a2 += ag * w4.z; a3 += ag * w4.w;
            accc += ag * (b_in[d] + bo[d]);
            accg += ag;
            accb1 += a * b1[d];
        }
        float* red  = smem;                    // [4][8][33]
        float* red2 = smem + 4 * 8 * 33;       // [4][8][3]
        int rb = (row * 8 + kc) * 33 + j4 * 4;
        red[rb + 0] = a0; red[rb + 1] = a1; red[rb + 2] = a2; red[rb + 3] = a3;
        if (j4 == 0) {
            int b2 = (row * 8 + kc) * 3;
            red2[b2 + 0] = accc; red2[b2 + 1] = accg; red2[b2 + 2] = accb1;
        }
        __syncthreads();
        if (tid < 128) {
            int r = tid >> 5, j = tid & 31;
            float s = 0.f;
            #pragma unroll
            for (int k2 = 0; k2 < 8; ++k2) s += red[(r * 8 + k2) * 33 + j];
            wf1x[(e0 + r) * INDIM + j] = s;
        } else if (tid < 132) {
            int r = tid - 128;
            float sc = 0.f, sg = 0.f, sb = 0.f;
            #pragma unroll
            for (int k2 = 0; k2 < 8; ++k2) {
                int b2 = (r * 8 + k2) * 3;
                sc += red2[b2 + 0]; sg += red2[b2 + 1]; sb += red2[b2 + 2];
            }
            int e = e0 + r;
            wf1c[e] = sc; wg1[e] = sg; wb1[e] = sb;
            bb[e] = b_in[e] + bo[e];
        }
    } else {
        // transpose+cvt: MT[k][d] = bf16(M[d][k] * (m==1 ? g1[k] : 1)); 64x64 tiles
        int t = bid - 512;             // 0..191
        int m = t >> 6;                // 0 wo, 1 wff1*g1, 2 wff2
        int tt = t & 63;
        int r = tt >> 3, c = tt & 7;   // d-tile, k-tile
        const float* M = (m == 0) ? wo : (m == 1 ? wff1 : wff2);
        u16* MT = (m == 0) ? woT : (m == 1 ? wff1g1T : wff2T);
        float* tile = smem;            // [64][65]
        int rr = tid >> 2, cc = (tid & 3) * 16;
        const float* src = M + (long)(r * 64 + rr) * DIM + c * 64 + cc;
        #pragma unroll
        for (int i = 0; i < 4; ++i) {
            float4 v = *(const float4*)(src + i * 4);
            tile[rr * 65 + cc + i * 4 + 0] = v.x;
            tile[rr * 65 + cc + i * 4 + 1] = v.y;
            tile[rr * 65 + cc + i * 4 + 2] = v.z;
            tile[rr * 65 + cc + i * 4 + 3] = v.w;
        }
        __syncthreads();
        int orr = tid >> 2, occ = (tid & 3) * 16;   // k-local, d-chunk
        float gk = (m == 1) ? g1[c * 64 + orr] : 1.f;
        u16 ob[16];
        #pragma unroll
        for (int i = 0; i < 16; ++i) ob[i] = f2bf(tile[(occ + i) * 65 + orr] * gk);
        u16* dst = MT + (long)(c * 64 + orr) * DIM + r * 64 + occ;
        *(ushort8*)dst = *(ushort8*)ob;
        *(ushort8*)(dst + 8) = *(ushort8*)(ob + 8);
    }
}

// ===================== k_w: 512 token tiles (q0 computed in-block from wq2) =====================
__global__ __launch_bounds__(256) void k_w(
    const float* __restrict__ x,
    const float* __restrict__ wq2, const float* __restrict__ bq2,
    const u16* __restrict__ wk2b, const float* __restrict__ bk2,
    float* __restrict__ xup, float* __restrict__ zdp) {
    __shared__ u16 sB[DIM * 40];       // 40960 B
    __shared__ float s_q0[DIM];        // 2048
    __shared__ float sw[WBM];          // 512
    __shared__ float sxu8[8][32];      // 1024
    __shared__ float szz[8];           // 32
    __shared__ float sx0[INDIM];       // 128
    int tid = threadIdx.x;
    int tt = blockIdx.x;
    int lane = tid & 63, wid = tid >> 6;
    long tbase = (long)tt * WBM;
    int batch = (int)(tbase >> 12);

    #pragma unroll
    for (int pp = 0; pp < 8; ++pp) {
        int f = (pp * 256 + tid) * 8;
        int row = f >> 5, colc = f & 31;
        ushort8 v = *(const ushort8*)(wk2b + f);
        *(ushort8*)(sB + row * 40 + colc) = v;
    }
    if (tid < INDIM) sx0[tid] = x[(long)batch * SEQ * INDIM + tid];
    __syncthreads();
    #pragma unroll
    for (int rep = 0; rep < 2; ++rep) {
        int e = tid + rep * 256;
        float a = bq2[e] + dot32(wq2 + e * INDIM, sx0);
        s_q0[e] = (a > 0.f) ? (a + 1.f) : __expf(a);
    }

    int col = lane & 15;
    int koff = (lane >> 4) * 8;
    bf16x8 fa[2];
    #pragma unroll
    for (int mi = 0; mi < 2; ++mi) {
        const float* xr = x + (tbase + wid * 32 + mi * 16 + col) * INDIM + koff;
        float4 a0 = *(const float4*)(xr);
        float4 a1 = *(const float4*)(xr + 4);
        u16 tmp[8] = { f2bf(a0.x), f2bf(a0.y), f2bf(a0.z), f2bf(a0.w),
                       f2bf(a1.x), f2bf(a1.y), f2bf(a1.z), f2bf(a1.w) };
        fa[mi] = *(bf16x8*)tmp;
    }
    __syncthreads();

    float q0v[32], bkv[32];
    #pragma unroll
    for (int ni = 0; ni < 32; ++ni) {
        q0v[ni] = s_q0[ni * 16 + col];
        bkv[ni] = bk2[ni * 16 + col];
    }

    f32x4 zero = {0.f, 0.f, 0.f, 0.f};
    float wpart[2][4] = {};
    #pragma unroll
    for (int nc = 0; nc < 4; ++nc) {
        bf16x8 fb[8];
        #pragma unroll
        for (int nj = 0; nj < 8; ++nj) {
            int row = (nc * 8 + nj) * 16 + col;
            fb[nj] = *(const bf16x8*)(sB + row * 40 + koff);
        }
        #pragma unroll
        for (int mi = 0; mi < 2; ++mi) {
            #pragma unroll
            for (int nj = 0; nj < 8; ++nj) {
                f32x4 acc = __builtin_amdgcn_mfma_f32_16x16x32_bf16(fa[mi], fb[nj], zero, 0, 0, 0);
                int ni = nc * 8 + nj;
                #pragma unroll
                for (int r = 0; r < 4; ++r) {
                    float v = acc[r] + bkv[ni];
                    v = (v > 0.f) ? (v + 1.f) : __expf(v);
                    wpart[mi][r] += v * q0v[ni];
                }
            }
        }
    }
    #pragma unroll
    for (int mi = 0; mi < 2; ++mi) {
        #pragma unroll
        for (int r = 0; r < 4; ++r) {
            float s = wpart[mi][r];
            s += __shfl_xor(s, 1, 64); s += __shfl_xor(s, 2, 64);
            s += __shfl_xor(s, 4, 64); s += __shfl_xor(s, 8, 64);
            if (col == 0) sw[wid * 32 + mi * 16 + (lane >> 4) * 4 + r] = s;
        }
    }
    __syncthreads();
    {
        int j = tid & 31, g = tid >> 5;
        float a = 0.f, z = 0.f;
        for (int tl = g; tl < WBM; tl += 8) {
            float wv_ = sw[tl];
            a += wv_ * x[(tbase + tl) * INDIM + j];
            if (j == 0) z += wv_;
        }
        sxu8[g][j] = a;
        if (j == 0) szz[g] = z;
    }
    __syncthreads();
    if (tid < 32) {
        float a = 0.f;
        #pragma unroll
        for (int g = 0; g < 8; ++g) a += sxu8[g][tid];
        xup[tt * INDIM + tid] = a;
    } else if (tid == 32) {
        float z = 0.f;
        #pragma unroll
        for (int g = 0; g < 8; ++g) z += szz[g];
        zdp[tt] = z;
    }
}

// ===================== k_final: 3 coalesced GEMVs + LNs =====================
__device__ __forceinline__ void reduce2_512(float a, float b, int tid, float* l16,
                                            float& oa, float& ob) {
    #pragma unroll
    for (int off = 1; off < 64; off <<= 1) {
        a += __shfl_xor(a, off, 64);
        b += __shfl_xor(b, off, 64);
    }
    int w = tid >> 6;
    if ((tid & 63) == 0) { l16[w] = a; l16[8 + w] = b; }
    __syncthreads();
    float ra = 0.f, rb = 0.f;
    #pragma unroll
    for (int i = 0; i < 8; ++i) { ra += l16[i]; rb += l16[8 + i]; }
    oa = ra; ob = rb;
    __syncthreads();
}

// coalesced GEMV: out_d = sum_k MT[k][d] * vec[k]; 8-way k-split, 512 threads.
__device__ __forceinline__ float gemv512(const u16* __restrict__ MT,
                                         const float* __restrict__ vec,
                                         float* __restrict__ spart,
                                         int tid, int d) {
    int kc = tid >> 6, dg = tid & 63;
    float ps[8] = {};
    const u16* base = MT + (long)(kc * 64) * DIM + dg * 8;
    #pragma unroll 8
    for (int k8 = 0; k8 < 64; ++k8) {
        ushort8 w8 = *(const ushort8*)(base + (long)k8 * DIM);
        float fk = vec[kc * 64 + k8];
        #pragma unroll
        for (int j = 0; j < 8; ++j) ps[j] += bf2f(w8[j]) * fk;
    }
    #pragma unroll
    for (int j = 0; j < 8; ++j) spart[kc * DIM + dg * 8 + j] = ps[j];
    __syncthreads();
    float acc = 0.f;
    #pragma unroll
    for (int i = 0; i < 8; ++i) acc += spart[i * DIM + d];
    return acc;
}

__global__ __launch_bounds__(512) void k_final(
    const float* __restrict__ x, const float* __restrict__ w_in,
    const float* __restrict__ wv2, const float* __restrict__ wvb,
    const float* __restrict__ bb,
    const float* __restrict__ wf1x, const float* __restrict__ wf1c,
    const float* __restrict__ wg1, const float* __restrict__ wb1,
    const float* __restrict__ g1, const float* __restrict__ b1,
    const float* __restrict__ bff1, const float* __restrict__ bff2,
    const u16* __restrict__ woT, const u16* __restrict__ wff1g1T,
    const u16* __restrict__ wff2T,
    const float* __restrict__ g2, const float* __restrict__ b2,
    const float* __restrict__ gf, const float* __restrict__ bfv,
    const float* __restrict__ wfc, const float* __restrict__ bfc,
    const float* __restrict__ xup, const float* __restrict__ zdp,
    float* __restrict__ out) {
    __shared__ float sx0[INDIM], sxu[INDIM];
    __shared__ float sv[DIM];
    __shared__ float sf[DIM];
    __shared__ float spart[8 * DIM];   // 16 KiB
    __shared__ float l16[16];
    __shared__ float szd;
    int n = blockIdx.x, tid = threadIdx.x, d = tid;
    if (tid < INDIM) {
        float a = 0.f;
        #pragma unroll 8
        for (int slot = 0; slot < 32; ++slot)
            a += xup[(n * 32 + slot) * INDIM + tid];
        sxu[tid] = a;
        sx0[tid] = x[(long)n * SEQ * INDIM + tid];
    } else if (tid == 32) {
        float z = 0.f;
        #pragma unroll 8
        for (int slot = 0; slot < 32; ++slot) z += zdp[n * 32 + slot];
        szd = z;
    }
    __syncthreads();
    float zd = szd;
    float Z = 1.f / (zd + 1e-6f);
    float zz = zd * Z;

    // u2 = wv2 @ xu ; GEMV-A input v = Z*u2 + zz*wvb
    float u2d = dot32(wv2 + d * INDIM, sxu);
    sv[d] = Z * u2d + zz * wvb[d];
    __syncthreads();

    // o = wo @ v  (coalesced woT)
    float o_d = gemv512(woT, sv, spart, tid, d);

    // r = bb + w_in@x0 + o ; LN1  (reduce's syncs also fence spart reuse)
    float rd = bb[d] + dot32(w_in + d * INDIM, sx0) + o_d;
    sv[d] = o_d;   // GEMV-B input (g1 folded into wff1g1T)
    float sum, sumsq;
    reduce2_512(rd, rd * rd, tid, l16, sum, sumsq);
    float mu1 = sum * (1.f / DIM);
    float s1 = rsqrtf(sumsq * (1.f / DIM) - mu1 * mu1 + 1e-5f);
    float r1 = (rd - mu1) * s1 * g1[d] + b1[d];

    // G = wf1x@x0 + (wff1*g1)@o + wf1c ; fpre ; f = relu
    float W_d = gemv512(wff1g1T, sv, spart, tid, d);
    float G = dot32(wf1x + d * INDIM, sx0) + W_d + wf1c[d];
    float fp = s1 * (G - mu1 * wg1[d]) + wb1[d] + bff1[d];
    __syncthreads();            // fence spart reads before GEMV-C writes
    sf[d] = fmaxf(fp, 0.f);
    __syncthreads();

    // y = r1 + wff2@f + bff2
    float yacc = gemv512(wff2T, sf, spart, tid, d);
    float y = r1 + bff2[d] + yacc;

    reduce2_512(y, y * y, tid, l16, sum, sumsq);
    float mu2 = sum * (1.f / DIM);
    float inv2 = rsqrtf(sumsq * (1.f / DIM) - mu2 * mu2 + 1e-5f);
    float h2 = (y - mu2) * inv2 * g2[d] + b2[d];

    reduce2_512(h2, h2 * h2, tid, l16, sum, sumsq);
    float mu3 = sum * (1.f / DIM);
    float inv3 = rsqrtf(sumsq * (1.f / DIM) - mu3 * mu3 + 1e-5f);
    float h3 = (h2 - mu3) * inv3 * gf[d] + bfv[d];

    float pfc = wfc[d] * h3;
    float dummy;
    reduce2_512(pfc, 0.f, tid, l16, sum, dummy);
    if (tid == 0) out[n] = sum + bfc[0];
}

extern "C" void kernel_launch(void* const* d_in, const int* in_sizes, int n_in,
                              void* d_out, int out_size, void* d_ws, size_t ws_size,
                              hipStream_t stream) {
    const float* x    = (const float*)d_in[0];
    const float* w_in = (const float*)d_in[1];
    const float* b_in = (const float*)d_in[2];
    const float* wq   = (const float*)d_in[3];
    const float* bq   = (const float*)d_in[4];
    const float* wk   = (const float*)d_in[5];
    const float* bk   = (const float*)d_in[6];
    const float* wv   = (const float*)d_in[7];
    const float* bv   = (const float*)d_in[8];
    const float* wo   = (const float*)d_in[9];
    const float* bo   = (const float*)d_in[10];
    const float* g1   = (const float*)d_in[11];
    const float* b1   = (const float*)d_in[12];
    const float* wff1 = (const float*)d_in[13];
    const float* bff1 = (const float*)d_in[14];
    const float* wff2 = (const float*)d_in[15];
    const float* bff2 = (const float*)d_in[16];
    const float* g2   = (const float*)d_in[17];
    const float* b2   = (const float*)d_in[18];
    const float* gf   = (const float*)d_in[19];
    const float* bf   = (const float*)d_in[20];
    const float* wfc  = (const float*)d_in[21];
    const float* bfc  = (const float*)d_in[22];

    char* ws = (char*)d_ws;
    float* wq2     = (float*)(ws + 0);         // 64 KiB
    float* bq2     = (float*)(ws + 65536);     // 2 KiB
    u16*   wk2b    = (u16*)  (ws + 67584);     // 32 KiB
    float* bk2     = (float*)(ws + 100352);    // 2 KiB
    float* wv2     = (float*)(ws + 102400);    // 64 KiB
    float* wvb     = (float*)(ws + 167936);    // 2 KiB
    float* bb      = (float*)(ws + 169984);    // 2 KiB
    float* wf1x    = (float*)(ws + 172032);    // 64 KiB
    float* wf1c    = (float*)(ws + 237568);    // 2 KiB
    float* wg1     = (float*)(ws + 239616);    // 2 KiB
    float* wb1     = (float*)(ws + 241664);    // 2 KiB
    u16*   woT     = (u16*)  (ws + 243712);    // 512 KiB
    u16*   wff1g1T = (u16*)  (ws + 767872);    // 512 KiB
    u16*   wff2T   = (u16*)  (ws + 1292160);   // 512 KiB
    float* xup     = (float*)(ws + 1816448);   // 64 KiB  [512][32]
    float* zdp     = (float*)(ws + 1881984);   // 2 KiB   [512]

    k_p1<<<704, 256, 0, stream>>>(x, w_in, b_in, wq, bq, wk, bk, wv, bv, wo, bo,
                                  g1, b1, wff1, wff2,
                                  wq2, bq2, wk2b, bk2, wv2, wvb,
                                  wf1x, wf1c, wg1, wb1, bb,
                                  woT, wff1g1T, wff2T);
    k_w<<<NTILE, 256, 0, stream>>>(x, wq2, bq2, wk2b, bk2, xup, zdp);
    k_final<<<NB, 512, 0, stream>>>(x, w_in, wv2, wvb, bb, wf1x, wf1c, wg1, wb1,
                                    g1, b1, bff1, bff2, woT, wff1g1T, wff2T,
                                    g2, b2, gf, bf, wfc, bfc, xup, zdp,
                                    (float*)d_out);
}